// Round 1
// baseline (543.340 us; speedup 1.0000x reference)
//
#include <hip/hip_runtime.h>

#define EDIM 1024
#define LNUM 24
#define FDIM 4096

__device__ __forceinline__ float wave_sum(float v) {
#pragma unroll
    for (int off = 32; off > 0; off >>= 1) v += __shfl_xor(v, off, 64);
    return v;
}

// Block-wide LayerNorm over 1024 elements with 256 threads.
// Loads xg[1024], writes normalized result to lds_out[1024]. red = 8-float LDS scratch.
__device__ __forceinline__ void block_ln(const float* __restrict__ xg,
                                         const float* __restrict__ w,
                                         const float* __restrict__ b,
                                         float* lds_out, float* red) {
    const int t = threadIdx.x;
    const float4 xv = reinterpret_cast<const float4*>(xg)[t];
    float s = xv.x + xv.y + xv.z + xv.w;
    s = wave_sum(s);
    const int wid = t >> 6;
    if ((t & 63) == 0) red[wid] = s;
    __syncthreads();
    const float mu = (red[0] + red[1] + red[2] + red[3]) * (1.0f / 1024.0f);
    const float dx = xv.x - mu, dy = xv.y - mu, dz = xv.z - mu, dw = xv.w - mu;
    float s2 = dx * dx + dy * dy + dz * dz + dw * dw;
    s2 = wave_sum(s2);
    if ((t & 63) == 0) red[4 + wid] = s2;
    __syncthreads();
    const float var = (red[4] + red[5] + red[6] + red[7]) * (1.0f / 1024.0f);
    const float inv = rsqrtf(var + 1e-5f);
    const float4 wv = reinterpret_cast<const float4*>(w)[t];
    const float4 bv = reinterpret_cast<const float4*>(b)[t];
    float4 o;
    o.x = dx * inv * wv.x + bv.x;
    o.y = dy * inv * wv.y + bv.y;
    o.z = dz * inv * wv.z + bv.z;
    o.w = dw * inv * wv.w + bv.w;
    reinterpret_cast<float4*>(lds_out)[t] = o;
    __syncthreads();
}

// One wave computes dot(Wrow[0:1024], op[0:1024]); op in LDS.
__device__ __forceinline__ float row_dot_1024(const float* __restrict__ Wrow,
                                              const float* lds_op) {
    const int lane = threadIdx.x & 63;
    float acc = 0.0f;
#pragma unroll
    for (int j = 0; j < 4; ++j) {
        const float4 wv = reinterpret_cast<const float4*>(Wrow)[lane + j * 64];
        const float4 ov = reinterpret_cast<const float4*>(lds_op)[lane + j * 64];
        acc += wv.x * ov.x + wv.y * ov.y + wv.z * ov.z + wv.w * ov.w;
    }
    return wave_sum(acc);
}

__device__ __forceinline__ float row_dot_4096(const float* __restrict__ Wrow,
                                              const float* lds_op) {
    const int lane = threadIdx.x & 63;
    float acc = 0.0f;
#pragma unroll
    for (int j = 0; j < 16; ++j) {
        const float4 wv = reinterpret_cast<const float4*>(Wrow)[lane + j * 64];
        const float4 ov = reinterpret_cast<const float4*>(lds_op)[lane + j * 64];
        acc += wv.x * ov.x + wv.y * ov.y + wv.z * ov.z + wv.w * ov.w;
    }
    return wave_sum(acc);
}

// ---------------- Stage 1: LN1 + k/v/r matvecs ----------------
// grid = 768 blocks: blocks [0,256) -> kw0 (k), [256,512) -> kw1 (v), [512,768) -> kw2 (r)
__global__ __launch_bounds__(256) void s1_kernel(
    const float* __restrict__ cx, const float* __restrict__ ln1w_l,
    const float* __restrict__ ln1b_l, const float* __restrict__ key_l,
    const float* __restrict__ statea_l, const float* __restrict__ mixk_l,
    const float* __restrict__ mixv_l, const float* __restrict__ mixr_l,
    float* __restrict__ kbuf, float* __restrict__ vbuf, float* __restrict__ rbuf,
    float* __restrict__ sa_out) {
    __shared__ float xn[EDIM];
    __shared__ float op[EDIM];
    __shared__ float red[8];
    const int b = blockIdx.x;
    const int mat = b >> 8;
    const int rb = (b & 255) * 4;
    block_ln(cx, ln1w_l, ln1b_l, xn, red);
    const int t = threadIdx.x;
    const float4 x4 = reinterpret_cast<float4*>(xn)[t];
    if (b == 0) reinterpret_cast<float4*>(sa_out)[t] = x4;  // sa = xn
    const float* mix = (mat == 0) ? mixk_l : (mat == 1) ? mixv_l : mixr_l;
    const float4 m4 = reinterpret_cast<const float4*>(mix)[t];
    const float4 s4 = reinterpret_cast<const float4*>(statea_l)[t];
    float4 o4;
    o4.x = x4.x + m4.x * s4.x;
    o4.y = x4.y + m4.y * s4.y;
    o4.z = x4.z + m4.z * s4.z;
    o4.w = x4.w + m4.w * s4.w;
    reinterpret_cast<float4*>(op)[t] = o4;
    __syncthreads();
    const int row = rb + (t >> 6);
    const float* Wrow = key_l + (size_t)mat * EDIM * EDIM + (size_t)row * EDIM;
    const float dot = row_dot_1024(Wrow, op);
    if ((t & 63) == 0) {
        if (mat == 0)
            kbuf[row] = expf(dot);
        else if (mat == 1)
            vbuf[row] = dot;
        else
            rbuf[row] = expf(dot) + 1.0f;
    }
}

// ---------------- Stage 2: WKV elementwise + ow matvec + residual ----------------
// grid = 256 blocks (4 rows each of ow)
__global__ __launch_bounds__(256) void s2_kernel(
    const float* __restrict__ cx, const float* __restrict__ kbuf,
    const float* __restrict__ vbuf, const float* __restrict__ rbuf,
    const float* __restrict__ tf_l, const float* __restrict__ td_l,
    const float* __restrict__ sb_l, const float* __restrict__ sc_l,
    const float* __restrict__ ow_l, float* __restrict__ sx,
    float* __restrict__ sb_out, float* __restrict__ sc_out) {
    __shared__ float g[EDIM];
    const int t = threadIdx.x;
    const int b = blockIdx.x;
    const float4 k4 = reinterpret_cast<const float4*>(kbuf)[t];
    const float4 v4 = reinterpret_cast<const float4*>(vbuf)[t];
    const float4 r4 = reinterpret_cast<const float4*>(rbuf)[t];
    const float4 tf4 = reinterpret_cast<const float4*>(tf_l)[t];
    const float4 sb4 = reinterpret_cast<const float4*>(sb_l)[t];
    const float4 sc4 = reinterpret_cast<const float4*>(sc_l)[t];
    float4 g4;
    g4.x = (sb4.x + tf4.x * k4.x * v4.x) / (sc4.x * r4.x + tf4.x * k4.x * r4.x);
    g4.y = (sb4.y + tf4.y * k4.y * v4.y) / (sc4.y * r4.y + tf4.y * k4.y * r4.y);
    g4.z = (sb4.z + tf4.z * k4.z * v4.z) / (sc4.z * r4.z + tf4.z * k4.z * r4.z);
    g4.w = (sb4.w + tf4.w * k4.w * v4.w) / (sc4.w * r4.w + tf4.w * k4.w * r4.w);
    reinterpret_cast<float4*>(g)[t] = g4;
    if (b == 0) {
        const float4 td4 = reinterpret_cast<const float4*>(td_l)[t];
        float4 nb, nc;
        nb.x = sb4.x * td4.x + k4.x * v4.x;
        nb.y = sb4.y * td4.y + k4.y * v4.y;
        nb.z = sb4.z * td4.z + k4.z * v4.z;
        nb.w = sb4.w * td4.w + k4.w * v4.w;
        nc.x = sc4.x * td4.x + k4.x;
        nc.y = sc4.y * td4.y + k4.y;
        nc.z = sc4.z * td4.z + k4.z;
        nc.w = sc4.w * td4.w + k4.w;
        reinterpret_cast<float4*>(sb_out)[t] = nb;
        reinterpret_cast<float4*>(sc_out)[t] = nc;
    }
    __syncthreads();
    const int row = b * 4 + (t >> 6);
    const float dot = row_dot_1024(ow_l + (size_t)row * EDIM, g);
    if ((t & 63) == 0) sx[row] = cx[row] + dot;
}

// ---------------- Stage 3: LN2 + kfw/rfw matvecs ----------------
// grid = 1280 blocks: [0,1024) -> kfw rows (4 each), [1024,1280) -> rfw rows
__global__ __launch_bounds__(256) void s3_kernel(
    const float* __restrict__ sx, const float* __restrict__ ln2w_l,
    const float* __restrict__ ln2b_l, const float* __restrict__ stated_l,
    const float* __restrict__ mixkf_l, const float* __restrict__ mixrf_l,
    const float* __restrict__ kfw_l, const float* __restrict__ rfw_l,
    float* __restrict__ kfbuf, float* __restrict__ rdivbuf,
    float* __restrict__ sd_out) {
    __shared__ float x2[EDIM];
    __shared__ float op[EDIM];
    __shared__ float red[8];
    const int b = blockIdx.x;
    block_ln(sx, ln2w_l, ln2b_l, x2, red);
    const int t = threadIdx.x;
    const bool isK = (b < 1024);
    const float4 x4 = reinterpret_cast<float4*>(x2)[t];
    if (b == 0) reinterpret_cast<float4*>(sd_out)[t] = x4;  // sd = x2
    const float* mix = isK ? mixkf_l : mixrf_l;
    const float4 m4 = reinterpret_cast<const float4*>(mix)[t];
    const float4 s4 = reinterpret_cast<const float4*>(stated_l)[t];
    float4 o4;
    o4.x = x4.x + m4.x * s4.x;
    o4.y = x4.y + m4.y * s4.y;
    o4.z = x4.z + m4.z * s4.z;
    o4.w = x4.w + m4.w * s4.w;
    reinterpret_cast<float4*>(op)[t] = o4;
    __syncthreads();
    const int wid = t >> 6;
    if (isK) {
        const int row = b * 4 + wid;
        const float dot = row_dot_1024(kfw_l + (size_t)row * EDIM, op);
        if ((t & 63) == 0) {
            const float rl = fmaxf(dot, 0.0f);
            kfbuf[row] = rl * rl;
        }
    } else {
        const int row = (b - 1024) * 4 + wid;
        const float dot = row_dot_1024(rfw_l + (size_t)row * EDIM, op);
        if ((t & 63) == 0) rdivbuf[row] = 1.0f / (1.0f + expf(dot));
    }
}

// ---------------- Stage 4: vfw matvec + gated residual ----------------
// grid = 256 blocks (4 rows each)
__global__ __launch_bounds__(256) void s4_kernel(
    const float* __restrict__ sx, const float* __restrict__ kfbuf,
    const float* __restrict__ rdivbuf, const float* __restrict__ vfw_l,
    float* __restrict__ xout) {
    __shared__ float op[FDIM];
    const int t = threadIdx.x;
    const int b = blockIdx.x;
#pragma unroll
    for (int j = 0; j < 4; ++j)
        reinterpret_cast<float4*>(op)[t + j * 256] =
            reinterpret_cast<const float4*>(kfbuf)[t + j * 256];
    __syncthreads();
    const int row = b * 4 + (t >> 6);
    const float dot = row_dot_4096(vfw_l + (size_t)row * FDIM, op);
    if ((t & 63) == 0) xout[row] = sx[row] + dot * rdivbuf[row];
}

extern "C" void kernel_launch(void* const* d_in, const int* in_sizes, int n_in,
                              void* d_out, int out_size, void* d_ws, size_t ws_size,
                              hipStream_t stream) {
    const float* x_in   = (const float*)d_in[0];
    const float* state  = (const float*)d_in[1];
    const float* ln1w   = (const float*)d_in[2];
    const float* ln1b   = (const float*)d_in[3];
    const float* ln2w   = (const float*)d_in[4];
    const float* ln2b   = (const float*)d_in[5];
    const float* td     = (const float*)d_in[6];
    const float* tf     = (const float*)d_in[7];
    const float* key    = (const float*)d_in[8];   // [L,3,E,E]
    const float* ow     = (const float*)d_in[9];   // [L,E,E]
    const float* mixk   = (const float*)d_in[10];
    const float* mixv   = (const float*)d_in[11];
    const float* mixr   = (const float*)d_in[12];
    const float* mixkf  = (const float*)d_in[13];
    const float* mixrf  = (const float*)d_in[14];
    const float* kffn   = (const float*)d_in[15];  // [L,F,E]
    const float* rffn   = (const float*)d_in[16];  // [L,E,E]
    const float* vffn   = (const float*)d_in[17];  // [L,E,F]

    float* out = (float*)d_out;
    float* xout_final = out;            // [E]
    float* sa_out = out + EDIM;         // [L,E]
    float* sb_out = sa_out + LNUM * EDIM;
    float* sc_out = sb_out + LNUM * EDIM;
    float* sd_out = sc_out + LNUM * EDIM;

    float* ws    = (float*)d_ws;
    float* xbuf  = ws;           // [E] residual stream
    float* sxbuf = ws + 1024;    // [E]
    float* kbuf  = ws + 2048;    // [E]
    float* vbuf  = ws + 3072;    // [E]
    float* rbuf  = ws + 4096;    // [E]
    float* kfbuf = ws + 5120;    // [F]
    float* rdiv  = ws + 9216;    // [E]

    for (int l = 0; l < LNUM; ++l) {
        const float* cx = (l == 0) ? x_in : xbuf;
        const float* statea_l = state + 0 * LNUM * EDIM + l * EDIM;
        const float* stateb_l = state + 1 * LNUM * EDIM + l * EDIM;
        const float* statec_l = state + 2 * LNUM * EDIM + l * EDIM;
        const float* stated_l = state + 3 * LNUM * EDIM + l * EDIM;

        s1_kernel<<<768, 256, 0, stream>>>(
            cx, ln1w + l * EDIM, ln1b + l * EDIM, key + (size_t)l * 3 * EDIM * EDIM,
            statea_l, mixk + l * EDIM, mixv + l * EDIM, mixr + l * EDIM,
            kbuf, vbuf, rbuf, sa_out + l * EDIM);

        s2_kernel<<<256, 256, 0, stream>>>(
            cx, kbuf, vbuf, rbuf, tf + l * EDIM, td + l * EDIM, stateb_l, statec_l,
            ow + (size_t)l * EDIM * EDIM, sxbuf, sb_out + l * EDIM, sc_out + l * EDIM);

        s3_kernel<<<1280, 256, 0, stream>>>(
            sxbuf, ln2w + l * EDIM, ln2b + l * EDIM, stated_l,
            mixkf + l * EDIM, mixrf + l * EDIM,
            kffn + (size_t)l * FDIM * EDIM, rffn + (size_t)l * EDIM * EDIM,
            kfbuf, rdiv, sd_out + l * EDIM);

        float* xo = (l == LNUM - 1) ? xout_final : xbuf;
        s4_kernel<<<256, 256, 0, stream>>>(
            sxbuf, kfbuf, rdiv, vffn + (size_t)l * EDIM * FDIM, xo);
    }
}

// Round 2
// 542.869 us; speedup vs baseline: 1.0009x; 1.0009x over previous
//
#include <hip/hip_runtime.h>

#define EDIM 1024
#define LNUM 24
#define FDIM 4096

__device__ __forceinline__ float wave_sum(float v) {
#pragma unroll
    for (int off = 32; off > 0; off >>= 1) v += __shfl_xor(v, off, 64);
    return v;
}

// Block-wide LayerNorm over 1024 elements with 256 threads.
// Loads xg[1024], writes normalized result to lds_out[1024]. red = 8-float LDS scratch.
__device__ __forceinline__ void block_ln(const float* __restrict__ xg,
                                         const float* __restrict__ w,
                                         const float* __restrict__ b,
                                         float* lds_out, float* red) {
    const int t = threadIdx.x;
    const float4 xv = reinterpret_cast<const float4*>(xg)[t];
    float s = xv.x + xv.y + xv.z + xv.w;
    s = wave_sum(s);
    const int wid = t >> 6;
    if ((t & 63) == 0) red[wid] = s;
    __syncthreads();
    const float mu = (red[0] + red[1] + red[2] + red[3]) * (1.0f / 1024.0f);
    const float dx = xv.x - mu, dy = xv.y - mu, dz = xv.z - mu, dw = xv.w - mu;
    float s2 = dx * dx + dy * dy + dz * dz + dw * dw;
    s2 = wave_sum(s2);
    if ((t & 63) == 0) red[4 + wid] = s2;
    __syncthreads();
    const float var = (red[4] + red[5] + red[6] + red[7]) * (1.0f / 1024.0f);
    const float inv = rsqrtf(var + 1e-5f);
    const float4 wv = reinterpret_cast<const float4*>(w)[t];
    const float4 bv = reinterpret_cast<const float4*>(b)[t];
    float4 o;
    o.x = dx * inv * wv.x + bv.x;
    o.y = dy * inv * wv.y + bv.y;
    o.z = dz * inv * wv.z + bv.z;
    o.w = dw * inv * wv.w + bv.w;
    reinterpret_cast<float4*>(lds_out)[t] = o;
    __syncthreads();
}

// One wave computes dot(Wrow[0:1024], op[0:1024]); op in LDS.
__device__ __forceinline__ float row_dot_1024(const float* __restrict__ Wrow,
                                              const float* lds_op) {
    const int lane = threadIdx.x & 63;
    float acc = 0.0f;
#pragma unroll
    for (int j = 0; j < 4; ++j) {
        const float4 wv = reinterpret_cast<const float4*>(Wrow)[lane + j * 64];
        const float4 ov = reinterpret_cast<const float4*>(lds_op)[lane + j * 64];
        acc += wv.x * ov.x + wv.y * ov.y + wv.z * ov.z + wv.w * ov.w;
    }
    return wave_sum(acc);
}

__device__ __forceinline__ float row_dot_4096(const float* __restrict__ Wrow,
                                              const float* lds_op) {
    const int lane = threadIdx.x & 63;
    float acc = 0.0f;
#pragma unroll
    for (int j = 0; j < 16; ++j) {
        const float4 wv = reinterpret_cast<const float4*>(Wrow)[lane + j * 64];
        const float4 ov = reinterpret_cast<const float4*>(lds_op)[lane + j * 64];
        acc += wv.x * ov.x + wv.y * ov.y + wv.z * ov.z + wv.w * ov.w;
    }
    return wave_sum(acc);
}

// ---------------- Stage 1: LN1 + k/v/r matvecs ----------------
// grid = 768 blocks: blocks [0,256) -> kw0 (k), [256,512) -> kw1 (v), [512,768) -> kw2 (r)
__global__ __launch_bounds__(256) void s1_kernel(
    const float* __restrict__ cx, const float* __restrict__ ln1w_l,
    const float* __restrict__ ln1b_l, const float* __restrict__ key_l,
    const float* __restrict__ statea_l, const float* __restrict__ mixk_l,
    const float* __restrict__ mixv_l, const float* __restrict__ mixr_l,
    float* __restrict__ kbuf, float* __restrict__ vbuf, float* __restrict__ rbuf,
    float* __restrict__ sa_out) {
    __shared__ float xn[EDIM];
    __shared__ float op[EDIM];
    __shared__ float red[8];
    const int b = blockIdx.x;
    const int mat = b >> 8;
    const int rb = (b & 255) * 4;
    block_ln(cx, ln1w_l, ln1b_l, xn, red);
    const int t = threadIdx.x;
    const float4 x4 = reinterpret_cast<float4*>(xn)[t];
    if (b == 0) reinterpret_cast<float4*>(sa_out)[t] = x4;  // sa = xn
    const float* mix = (mat == 0) ? mixk_l : (mat == 1) ? mixv_l : mixr_l;
    const float4 m4 = reinterpret_cast<const float4*>(mix)[t];
    const float4 s4 = reinterpret_cast<const float4*>(statea_l)[t];
    float4 o4;
    o4.x = x4.x + m4.x * s4.x;
    o4.y = x4.y + m4.y * s4.y;
    o4.z = x4.z + m4.z * s4.z;
    o4.w = x4.w + m4.w * s4.w;
    reinterpret_cast<float4*>(op)[t] = o4;
    __syncthreads();
    const int row = rb + (t >> 6);
    const float* Wrow = key_l + (size_t)mat * EDIM * EDIM + (size_t)row * EDIM;
    const float dot = row_dot_1024(Wrow, op);
    if ((t & 63) == 0) {
        if (mat == 0)
            kbuf[row] = expf(dot);
        else if (mat == 1)
            vbuf[row] = dot;
        else
            rbuf[row] = expf(dot) + 1.0f;
    }
}

// ---------------- Stage 2: WKV elementwise + ow matvec + residual ----------------
// grid = 256 blocks (4 rows each of ow)
__global__ __launch_bounds__(256) void s2_kernel(
    const float* __restrict__ cx, const float* __restrict__ kbuf,
    const float* __restrict__ vbuf, const float* __restrict__ rbuf,
    const float* __restrict__ tf_l, const float* __restrict__ td_l,
    const float* __restrict__ sb_l, const float* __restrict__ sc_l,
    const float* __restrict__ ow_l, float* __restrict__ sx,
    float* __restrict__ sb_out, float* __restrict__ sc_out) {
    __shared__ float g[EDIM];
    const int t = threadIdx.x;
    const int b = blockIdx.x;
    const float4 k4 = reinterpret_cast<const float4*>(kbuf)[t];
    const float4 v4 = reinterpret_cast<const float4*>(vbuf)[t];
    const float4 r4 = reinterpret_cast<const float4*>(rbuf)[t];
    const float4 tf4 = reinterpret_cast<const float4*>(tf_l)[t];
    const float4 sb4 = reinterpret_cast<const float4*>(sb_l)[t];
    const float4 sc4 = reinterpret_cast<const float4*>(sc_l)[t];
    float4 g4;
    g4.x = (sb4.x + tf4.x * k4.x * v4.x) / (sc4.x * r4.x + tf4.x * k4.x * r4.x);
    g4.y = (sb4.y + tf4.y * k4.y * v4.y) / (sc4.y * r4.y + tf4.y * k4.y * r4.y);
    g4.z = (sb4.z + tf4.z * k4.z * v4.z) / (sc4.z * r4.z + tf4.z * k4.z * r4.z);
    g4.w = (sb4.w + tf4.w * k4.w * v4.w) / (sc4.w * r4.w + tf4.w * k4.w * r4.w);
    reinterpret_cast<float4*>(g)[t] = g4;
    if (b == 0) {
        const float4 td4 = reinterpret_cast<const float4*>(td_l)[t];
        float4 nb, nc;
        nb.x = sb4.x * td4.x + k4.x * v4.x;
        nb.y = sb4.y * td4.y + k4.y * v4.y;
        nb.z = sb4.z * td4.z + k4.z * v4.z;
        nb.w = sb4.w * td4.w + k4.w * v4.w;
        nc.x = sc4.x * td4.x + k4.x;
        nc.y = sc4.y * td4.y + k4.y;
        nc.z = sc4.z * td4.z + k4.z;
        nc.w = sc4.w * td4.w + k4.w;
        reinterpret_cast<float4*>(sb_out)[t] = nb;
        reinterpret_cast<float4*>(sc_out)[t] = nc;
    }
    __syncthreads();
    const int row = b * 4 + (t >> 6);
    const float dot = row_dot_1024(ow_l + (size_t)row * EDIM, g);
    if ((t & 63) == 0) sx[row] = cx[row] + dot;
}

// ---------------- Stage 3: LN2 + kfw/rfw matvecs ----------------
// grid = 1280 blocks: [0,1024) -> kfw rows (4 each), [1024,1280) -> rfw rows
__global__ __launch_bounds__(256) void s3_kernel(
    const float* __restrict__ sx, const float* __restrict__ ln2w_l,
    const float* __restrict__ ln2b_l, const float* __restrict__ stated_l,
    const float* __restrict__ mixkf_l, const float* __restrict__ mixrf_l,
    const float* __restrict__ kfw_l, const float* __restrict__ rfw_l,
    float* __restrict__ kfbuf, float* __restrict__ rdivbuf,
    float* __restrict__ sd_out) {
    __shared__ float x2[EDIM];
    __shared__ float op[EDIM];
    __shared__ float red[8];
    const int b = blockIdx.x;
    block_ln(sx, ln2w_l, ln2b_l, x2, red);
    const int t = threadIdx.x;
    const bool isK = (b < 1024);
    const float4 x4 = reinterpret_cast<float4*>(x2)[t];
    if (b == 0) reinterpret_cast<float4*>(sd_out)[t] = x4;  // sd = x2
    const float* mix = isK ? mixkf_l : mixrf_l;
    const float4 m4 = reinterpret_cast<const float4*>(mix)[t];
    const float4 s4 = reinterpret_cast<const float4*>(stated_l)[t];
    float4 o4;
    o4.x = x4.x + m4.x * s4.x;
    o4.y = x4.y + m4.y * s4.y;
    o4.z = x4.z + m4.z * s4.z;
    o4.w = x4.w + m4.w * s4.w;
    reinterpret_cast<float4*>(op)[t] = o4;
    __syncthreads();
    const int wid = t >> 6;
    if (isK) {
        const int row = b * 4 + wid;
        const float dot = row_dot_1024(kfw_l + (size_t)row * EDIM, op);
        if ((t & 63) == 0) {
            const float rl = fmaxf(dot, 0.0f);
            kfbuf[row] = rl * rl;
        }
    } else {
        const int row = (b - 1024) * 4 + wid;
        const float dot = row_dot_1024(rfw_l + (size_t)row * EDIM, op);
        if ((t & 63) == 0) rdivbuf[row] = 1.0f / (1.0f + expf(dot));
    }
}

// ---------------- Stage 4: vfw matvec + gated residual ----------------
// grid = 256 blocks (4 rows each)
__global__ __launch_bounds__(256) void s4_kernel(
    const float* __restrict__ sx, const float* __restrict__ kfbuf,
    const float* __restrict__ rdivbuf, const float* __restrict__ vfw_l,
    float* __restrict__ xout) {
    __shared__ float op[FDIM];
    const int t = threadIdx.x;
    const int b = blockIdx.x;
#pragma unroll
    for (int j = 0; j < 4; ++j)
        reinterpret_cast<float4*>(op)[t + j * 256] =
            reinterpret_cast<const float4*>(kfbuf)[t + j * 256];
    __syncthreads();
    const int row = b * 4 + (t >> 6);
    const float dot = row_dot_4096(vfw_l + (size_t)row * FDIM, op);
    if ((t & 63) == 0) xout[row] = sx[row] + dot * rdivbuf[row];
}

extern "C" void kernel_launch(void* const* d_in, const int* in_sizes, int n_in,
                              void* d_out, int out_size, void* d_ws, size_t ws_size,
                              hipStream_t stream) {
    const float* x_in   = (const float*)d_in[0];
    const float* state  = (const float*)d_in[1];
    const float* ln1w   = (const float*)d_in[2];
    const float* ln1b   = (const float*)d_in[3];
    const float* ln2w   = (const float*)d_in[4];
    const float* ln2b   = (const float*)d_in[5];
    const float* td     = (const float*)d_in[6];
    const float* tf     = (const float*)d_in[7];
    const float* key    = (const float*)d_in[8];   // [L,3,E,E]
    const float* ow     = (const float*)d_in[9];   // [L,E,E]
    const float* mixk   = (const float*)d_in[10];
    const float* mixv   = (const float*)d_in[11];
    const float* mixr   = (const float*)d_in[12];
    const float* mixkf  = (const float*)d_in[13];
    const float* mixrf  = (const float*)d_in[14];
    const float* kffn   = (const float*)d_in[15];  // [L,F,E]
    const float* rffn   = (const float*)d_in[16];  // [L,E,E]
    const float* vffn   = (const float*)d_in[17];  // [L,E,F]

    float* out = (float*)d_out;
    float* xout_final = out;            // [E]
    float* sa_out = out + EDIM;         // [L,E]
    float* sb_out = sa_out + LNUM * EDIM;
    float* sc_out = sb_out + LNUM * EDIM;
    float* sd_out = sc_out + LNUM * EDIM;

    float* ws    = (float*)d_ws;
    float* xbuf  = ws;           // [E] residual stream
    float* sxbuf = ws + 1024;    // [E]
    float* kbuf  = ws + 2048;    // [E]
    float* vbuf  = ws + 3072;    // [E]
    float* rbuf  = ws + 4096;    // [E]
    float* kfbuf = ws + 5120;    // [F]
    float* rdiv  = ws + 9216;    // [E]

    for (int l = 0; l < LNUM; ++l) {
        const float* cx = (l == 0) ? x_in : xbuf;
        const float* statea_l = state + 0 * LNUM * EDIM + l * EDIM;
        const float* stateb_l = state + 1 * LNUM * EDIM + l * EDIM;
        const float* statec_l = state + 2 * LNUM * EDIM + l * EDIM;
        const float* stated_l = state + 3 * LNUM * EDIM + l * EDIM;

        s1_kernel<<<768, 256, 0, stream>>>(
            cx, ln1w + l * EDIM, ln1b + l * EDIM, key + (size_t)l * 3 * EDIM * EDIM,
            statea_l, mixk + l * EDIM, mixv + l * EDIM, mixr + l * EDIM,
            kbuf, vbuf, rbuf, sa_out + l * EDIM);

        s2_kernel<<<256, 256, 0, stream>>>(
            cx, kbuf, vbuf, rbuf, tf + l * EDIM, td + l * EDIM, stateb_l, statec_l,
            ow + (size_t)l * EDIM * EDIM, sxbuf, sb_out + l * EDIM, sc_out + l * EDIM);

        s3_kernel<<<1280, 256, 0, stream>>>(
            sxbuf, ln2w + l * EDIM, ln2b + l * EDIM, stated_l,
            mixkf + l * EDIM, mixrf + l * EDIM,
            kffn + (size_t)l * FDIM * EDIM, rffn + (size_t)l * EDIM * EDIM,
            kfbuf, rdiv, sd_out + l * EDIM);

        float* xo = (l == LNUM - 1) ? xout_final : xbuf;
        s4_kernel<<<256, 256, 0, stream>>>(
            sxbuf, kfbuf, rdiv, vffn + (size_t)l * EDIM * FDIM, xo);
    }
}